// Round 8
// baseline (122.964 us; speedup 1.0000x reference)
//
#include <hip/hip_runtime.h>

#define NB 2
#define NH 16
#define SEQ 4096
#define HD 64
#define DIM 1024
#define WIN 512

typedef float f32x16 __attribute__((ext_vector_type(16)));
typedef short bf16x8 __attribute__((ext_vector_type(8)));
typedef unsigned int u32x4 __attribute__((ext_vector_type(4)));
typedef unsigned int u32x2 __attribute__((ext_vector_type(2)));
typedef unsigned short u16;
typedef unsigned int u32;

__device__ __forceinline__ u16 f2bf(float x) {
    u32 u = __float_as_uint(x);
    u += 0x7FFFu + ((u >> 16) & 1u);
    return (u16)(u >> 16);
}

// pack 2 f32 -> 1 u32 of 2 bf16 (RNE) in one VALU op
__device__ __forceinline__ u32 cvtpk(float lo, float hi) {
    u32 r;
    asm("v_cvt_pk_bf16_f32 %0, %1, %2" : "=v"(r) : "v"(lo), "v"(hi));
    return r;
}

// ---------------- trig table ----------------
__global__ void trig_kernel(float* __restrict__ ct, float* __restrict__ st) {
    int idx = blockIdx.x * 256 + threadIdx.x;   // 4096*32
    int s = idx >> 5, j = idx & 31;
    float inv = powf(1.0f / 10000.0f, (float)j * (1.0f / 32.0f));
    float ang = (float)s * inv;
    ct[idx] = cosf(ang);
    st[idx] = sinf(ang);
}

// ---------------- q/k: l2-normalize + rope + scale -> bf16, head-major ----------------
__device__ __forceinline__ void norm_rope_row(const float* __restrict__ row,
                                              const float* __restrict__ cr,
                                              const float* __restrict__ sr,
                                              float scale, u16* __restrict__ dst, int a) {
    float4 u0 = *(const float4*)(row + 8 * a);
    float4 u1 = *(const float4*)(row + 8 * a + 4);
    float4 v0 = *(const float4*)(row + 32 + 8 * a);
    float4 v1 = *(const float4*)(row + 32 + 8 * a + 4);
    float x1[8] = {u0.x, u0.y, u0.z, u0.w, u1.x, u1.y, u1.z, u1.w};
    float x2[8] = {v0.x, v0.y, v0.z, v0.w, v1.x, v1.y, v1.z, v1.w};
    float ss = 0.f;
#pragma unroll
    for (int i = 0; i < 8; ++i) ss += x1[i] * x1[i] + x2[i] * x2[i];
    ss += __shfl_xor(ss, 1);
    ss += __shfl_xor(ss, 2);
    float rn = scale / fmaxf(sqrtf(ss), 1e-6f);
    u16 o1[8], o2[8];
#pragma unroll
    for (int i = 0; i < 8; ++i) {
        float c = cr[8 * a + i], sn = sr[8 * a + i];
        o1[i] = f2bf((x1[i] * c + x2[i] * sn) * rn);
        o2[i] = f2bf((x2[i] * c - x1[i] * sn) * rn);
    }
    uint4 w1, w2;
    w1.x = (u32)o1[0] | ((u32)o1[1] << 16); w1.y = (u32)o1[2] | ((u32)o1[3] << 16);
    w1.z = (u32)o1[4] | ((u32)o1[5] << 16); w1.w = (u32)o1[6] | ((u32)o1[7] << 16);
    w2.x = (u32)o2[0] | ((u32)o2[1] << 16); w2.y = (u32)o2[2] | ((u32)o2[3] << 16);
    w2.z = (u32)o2[4] | ((u32)o2[5] << 16); w2.w = (u32)o2[6] | ((u32)o2[7] << 16);
    *(uint4*)(dst + 8 * a) = w1;
    *(uint4*)(dst + 32 + 8 * a) = w2;
}

__global__ void qk_prep(const float* __restrict__ xq, const float* __restrict__ xk,
                        const float* __restrict__ ctab, const float* __restrict__ stab,
                        u16* __restrict__ Qn, u16* __restrict__ Kn) {
    int bid = blockIdx.x;             // 2048 = 32 bh * 64 s-tiles
    int bh = bid >> 6, stile = bid & 63;
    int b = bh >> 4, h = bh & 15;
    int t = threadIdx.x;
    int lr = t >> 2, a = t & 3;
    int s = stile * 64 + lr;
    size_t inoff = ((size_t)(b * SEQ + s)) * DIM + h * HD;
    size_t outoff = ((size_t)bh * SEQ + s) * HD;
    const float* cr = ctab + (size_t)s * 32;
    const float* sr = stab + (size_t)s * 32;
    // fold 1/sqrt(64) * log2(e) into Q so softmax is raw exp2 with NO max shift
    norm_rope_row(xq + inoff, cr, sr, 0.125f * 1.44269504f, Qn + outoff, a);
    norm_rope_row(xk + inoff, cr, sr, 1.0f, Kn + outoff, a);
}

// ---------------- v: bf16 + transpose to Vt[bh][dim][s] ----------------
__global__ void v_prep(const float* __restrict__ xv, u16* __restrict__ Vt) {
    __shared__ u16 tile[64][66];
    int bid = blockIdx.x;
    int bh = bid >> 6, stile = bid & 63;
    int b = bh >> 4, h = bh & 15;
    int t = threadIdx.x;
    int lr = t >> 2, a = t & 3;
    int s = stile * 64 + lr;
    const float* vrow = xv + ((size_t)(b * SEQ + s)) * DIM + h * HD + 16 * a;
#pragma unroll
    for (int c = 0; c < 4; ++c) {
        float4 w = *(const float4*)(vrow + 4 * c);
        tile[lr][16 * a + 4 * c + 0] = f2bf(w.x);
        tile[lr][16 * a + 4 * c + 1] = f2bf(w.y);
        tile[lr][16 * a + 4 * c + 2] = f2bf(w.z);
        tile[lr][16 * a + 4 * c + 3] = f2bf(w.w);
    }
    __syncthreads();
    int d = t >> 2;
    u32 pk[8];
#pragma unroll
    for (int i = 0; i < 8; ++i) {
        u16 lo = tile[16 * a + 2 * i][d];
        u16 hi = tile[16 * a + 2 * i + 1][d];
        pk[i] = (u32)lo | ((u32)hi << 16);
    }
    u16* dst = Vt + ((size_t)bh * HD + d) * SEQ + stile * 64 + 16 * a;
    *(uint4*)(dst) = make_uint4(pk[0], pk[1], pk[2], pk[3]);
    *(uint4*)(dst + 8) = make_uint4(pk[4], pk[5], pk[6], pk[7]);
}

// ---------------- attention: swapped 32x32x16, fixed-shift softmax, K-prefetch pipeline ----------------
// grid = 32 bh * 32 q-tiles(128 rows) = 1024 blocks; 4 waves/block, each wave 32 q-rows
// launch_bounds (256,3): unified VGPR+AGPR cap ~170 — this kernel uses ~112+16(prefetch);
// (256,6)/(256,8) caps spilled the AGPR accumulators to scratch (r5/r6 post-mortems)
__global__ __launch_bounds__(256, 3) void attn_kernel(const u16* __restrict__ Qn,
                                                      const u16* __restrict__ Kn,
                                                      const u16* __restrict__ Vt,
                                                      float* __restrict__ out) {
    int phys = blockIdx.x;
    int logical = (phys & 7) * 128 + (phys >> 3);   // bijective: 1024 = 8 * 128
    int bh = logical >> 5, qt = logical & 31;
    int b = bh >> 4, h = bh & 15;
    int tid = threadIdx.x;
    int w = tid >> 6, l = tid & 63;
    int q = l & 31, hi = l >> 5;
    int qw0 = qt * 128 + w * 32;
    const u16* Qh = Qn + (size_t)bh * SEQ * HD;
    const u16* Kh = Kn + (size_t)bh * SEQ * HD;
    const u16* Vh = Vt + (size_t)bh * HD * SEQ;

    // Q B-fragments (col = q = lane&31, k-slot (hi,j) = dim kd*16 + hi*8 + j)
    const u16* qp = Qh + (size_t)(qw0 + q) * HD + hi * 8;
    bf16x8 qf0 = *(const bf16x8*)(qp);
    bf16x8 qf1 = *(const bf16x8*)(qp + 16);
    bf16x8 qf2 = *(const bf16x8*)(qp + 32);
    bf16x8 qf3 = *(const bf16x8*)(qp + 48);

    f32x16 acc0, acc1;
#pragma unroll
    for (int i = 0; i < 16; ++i) { acc0[i] = 0.f; acc1[i] = 0.f; }
    float l_ = 0.f;

    int t0 = (qw0 - (WIN - 1)) >> 5; if (t0 < 0) t0 = 0;
    int t1 = qw0 >> 5;
    int dq = qw0 + q;

    const u16* vrow0 = Vh + (size_t)(q) * SEQ;            // d = lane&31
    const u16* vrow1 = Vh + (size_t)(32 + q) * SEQ;       // d = 32 + lane&31
    const u16* krow = Kh + (size_t)q * HD + hi * 8;       // + kv0*HD per tile

    auto loadK = [&](int t, bf16x8 (&kr)[4]) {
        const u16* kp = krow + (size_t)(t << 5) * HD;
        kr[0] = *(const bf16x8*)(kp);
        kr[1] = *(const bf16x8*)(kp + 16);
        kr[2] = *(const bf16x8*)(kp + 32);
        kr[3] = *(const bf16x8*)(kp + 48);
    };

    auto body = [&](int t, const bf16x8 (&kr)[4], bool mask) {
        int kv0 = t << 5;
        // V fragments issued at tile start; consumed ~400cy later after softmax
        const u16* v0p = vrow0 + kv0 + hi * 8;
        const u16* v1p = vrow1 + kv0 + hi * 8;
        bf16x8 va0a = *(const bf16x8*)(v0p);
        bf16x8 va0b = *(const bf16x8*)(v0p + 16);
        bf16x8 va1a = *(const bf16x8*)(v1p);
        bf16x8 va1b = *(const bf16x8*)(v1p + 16);

        // --- QK^T (swapped): S^T[key][q] ---
        f32x16 st;
#pragma unroll
        for (int i = 0; i < 16; ++i) st[i] = 0.f;
        st = __builtin_amdgcn_mfma_f32_32x32x16_bf16(kr[0], qf0, st, 0, 0, 0);
        st = __builtin_amdgcn_mfma_f32_32x32x16_bf16(kr[1], qf1, st, 0, 0, 0);
        st = __builtin_amdgcn_mfma_f32_32x32x16_bf16(kr[2], qf2, st, 0, 0, 0);
        st = __builtin_amdgcn_mfma_f32_32x32x16_bf16(kr[3], qf3, st, 0, 0, 0);

        // --- fixed-shift softmax: |S| <= 0.18 so p = exp2(S) directly, no max ---
        float p[16];
        int base = dq - (kv0 + 4 * hi);     // diff = base - koff
#pragma unroll
        for (int r = 0; r < 16; ++r) {
            float e = exp2f(st[r]);
            if (mask) {
                int koff = (r & 3) + 8 * (r >> 2);
                p[r] = ((u32)(base - koff) < (u32)WIN) ? e : 0.f;
            } else {
                p[r] = e;
            }
        }
        float s01 = p[0] + p[1],  s23 = p[2] + p[3],  s45 = p[4] + p[5],  s67 = p[6] + p[7];
        float s89 = p[8] + p[9],  sab = p[10] + p[11], scd = p[12] + p[13], sef = p[14] + p[15];
        l_ += ((s01 + s23) + (s45 + s67)) + ((s89 + sab) + (scd + sef));

        // --- build P^T B-fragment in registers: cvt_pk + permlane32_swap (T12) ---
        u32 wd[8];
#pragma unroll
        for (int i = 0; i < 8; ++i) wd[i] = cvtpk(p[2 * i], p[2 * i + 1]);
        u32x4 b1, b2;
#if __has_builtin(__builtin_amdgcn_permlane32_swap)
        u32x2 sA = __builtin_amdgcn_permlane32_swap(wd[0], wd[2], false, false);
        u32x2 sB = __builtin_amdgcn_permlane32_swap(wd[1], wd[3], false, false);
        u32x2 sC = __builtin_amdgcn_permlane32_swap(wd[4], wd[6], false, false);
        u32x2 sD = __builtin_amdgcn_permlane32_swap(wd[5], wd[7], false, false);
        b1 = (u32x4){ sA[0], sB[0], sA[1], sB[1] };
        b2 = (u32x4){ sC[0], sD[0], sC[1], sD[1] };
#else
        u32 e0 = __shfl_xor(hi ? wd[0] : wd[2], 32);
        u32 e1 = __shfl_xor(hi ? wd[1] : wd[3], 32);
        u32 e2 = __shfl_xor(hi ? wd[4] : wd[6], 32);
        u32 e3 = __shfl_xor(hi ? wd[5] : wd[7], 32);
        b1 = (u32x4){ hi ? e0 : wd[0], hi ? e1 : wd[1], hi ? wd[2] : e0, hi ? wd[3] : e1 };
        b2 = (u32x4){ hi ? e2 : wd[4], hi ? e3 : wd[5], hi ? wd[6] : e2, hi ? wd[7] : e3 };
#endif
        bf16x8 pb1 = __builtin_bit_cast(bf16x8, b1);
        bf16x8 pb2 = __builtin_bit_cast(bf16x8, b2);

        // --- PV (swapped): O^T[d][q] += V^T P^T ---
        acc0 = __builtin_amdgcn_mfma_f32_32x32x16_bf16(va0a, pb1, acc0, 0, 0, 0);
        acc0 = __builtin_amdgcn_mfma_f32_32x32x16_bf16(va0b, pb2, acc0, 0, 0, 0);
        acc1 = __builtin_amdgcn_mfma_f32_32x32x16_bf16(va1a, pb1, acc1, 0, 0, 0);
        acc1 = __builtin_amdgcn_mfma_f32_32x32x16_bf16(va1b, pb2, acc1, 0, 0, 0);
    };

    // ---- depth-1 K-prefetch pipeline, unrolled x2 (static register ping-pong) ----
    bf16x8 ka[4], kb[4];
    loadK(t0, ka);
    int t = t0;
    for (;;) {
        if (t < t1) loadK(t + 1, kb);            // next K issues before this tile's softmax/PV
        body(t, ka, (t == t0) || (t == t1));
        if (++t > t1) break;
        if (t < t1) loadK(t + 1, ka);
        body(t, kb, (t == t1));
        if (++t > t1) break;
    }

    l_ += __shfl_xor(l_, 32);
    float inv = 1.0f / l_;
    float* orow = out + ((size_t)(b * SEQ + dq)) * DIM + h * HD;
#pragma unroll
    for (int g = 0; g < 4; ++g) {
        float4 v0 = { acc0[4 * g + 0] * inv, acc0[4 * g + 1] * inv,
                      acc0[4 * g + 2] * inv, acc0[4 * g + 3] * inv };
        float4 v1 = { acc1[4 * g + 0] * inv, acc1[4 * g + 1] * inv,
                      acc1[4 * g + 2] * inv, acc1[4 * g + 3] * inv };
        *(float4*)(orow + 8 * g + 4 * hi) = v0;          // d = 8g + 4hi + 0..3
        *(float4*)(orow + 32 + 8 * g + 4 * hi) = v1;     // d = 32 + 8g + 4hi + 0..3
    }
}

extern "C" void kernel_launch(void* const* d_in, const int* in_sizes, int n_in,
                              void* d_out, int out_size, void* d_ws, size_t ws_size,
                              hipStream_t stream) {
    (void)in_sizes; (void)n_in; (void)out_size; (void)ws_size;
    const float* xq = (const float*)d_in[0];
    const float* xk = (const float*)d_in[1];
    const float* xv = (const float*)d_in[2];
    float* out = (float*)d_out;

    const size_t HEADS_ELEMS = (size_t)NB * NH * SEQ * HD;   // 8,388,608
    u16* Qn = (u16*)d_ws;
    u16* Kn = Qn + HEADS_ELEMS;
    u16* Vt = Kn + HEADS_ELEMS;
    float* ctab = (float*)(Vt + HEADS_ELEMS);
    float* stab = ctab + (size_t)SEQ * 32;

    trig_kernel<<<dim3(512), dim3(256), 0, stream>>>(ctab, stab);
    qk_prep<<<dim3(2048), dim3(256), 0, stream>>>(xq, xk, ctab, stab, Qn, Kn);
    v_prep<<<dim3(2048), dim3(256), 0, stream>>>(xv, Vt);
    attn_kernel<<<dim3(1024), dim3(256), 0, stream>>>(Qn, Kn, Vt, out);
}

// Round 9
// 105.044 us; speedup vs baseline: 1.1706x; 1.1706x over previous
//
#include <hip/hip_runtime.h>

#define NB 2
#define NH 16
#define SEQ 4096
#define HD 64
#define DIM 1024
#define WIN 512

typedef float f32x16 __attribute__((ext_vector_type(16)));
typedef short bf16x8 __attribute__((ext_vector_type(8)));
typedef unsigned int u32x4 __attribute__((ext_vector_type(4)));
typedef unsigned int u32x2 __attribute__((ext_vector_type(2)));
typedef unsigned short u16;
typedef unsigned int u32;

__device__ __forceinline__ u16 f2bf(float x) {
    u32 u = __float_as_uint(x);
    u += 0x7FFFu + ((u >> 16) & 1u);
    return (u16)(u >> 16);
}

// pack 2 f32 -> 1 u32 of 2 bf16 (RNE) in one VALU op
__device__ __forceinline__ u32 cvtpk(float lo, float hi) {
    u32 r;
    asm("v_cvt_pk_bf16_f32 %0, %1, %2" : "=v"(r) : "v"(lo), "v"(hi));
    return r;
}

// ---------------- trig table ----------------
__global__ void trig_kernel(float* __restrict__ ct, float* __restrict__ st) {
    int idx = blockIdx.x * 256 + threadIdx.x;   // 4096*32
    int s = idx >> 5, j = idx & 31;
    float inv = powf(1.0f / 10000.0f, (float)j * (1.0f / 32.0f));
    float ang = (float)s * inv;
    ct[idx] = cosf(ang);
    st[idx] = sinf(ang);
}

// ---------------- q/k: l2-normalize + rope + scale -> bf16, head-major ----------------
__device__ __forceinline__ void norm_rope_row(const float* __restrict__ row,
                                              const float* __restrict__ cr,
                                              const float* __restrict__ sr,
                                              float scale, u16* __restrict__ dst, int a) {
    float4 u0 = *(const float4*)(row + 8 * a);
    float4 u1 = *(const float4*)(row + 8 * a + 4);
    float4 v0 = *(const float4*)(row + 32 + 8 * a);
    float4 v1 = *(const float4*)(row + 32 + 8 * a + 4);
    float x1[8] = {u0.x, u0.y, u0.z, u0.w, u1.x, u1.y, u1.z, u1.w};
    float x2[8] = {v0.x, v0.y, v0.z, v0.w, v1.x, v1.y, v1.z, v1.w};
    float ss = 0.f;
#pragma unroll
    for (int i = 0; i < 8; ++i) ss += x1[i] * x1[i] + x2[i] * x2[i];
    ss += __shfl_xor(ss, 1);
    ss += __shfl_xor(ss, 2);
    float rn = scale / fmaxf(sqrtf(ss), 1e-6f);
    u16 o1[8], o2[8];
#pragma unroll
    for (int i = 0; i < 8; ++i) {
        float c = cr[8 * a + i], sn = sr[8 * a + i];
        o1[i] = f2bf((x1[i] * c + x2[i] * sn) * rn);
        o2[i] = f2bf((x2[i] * c - x1[i] * sn) * rn);
    }
    uint4 w1, w2;
    w1.x = (u32)o1[0] | ((u32)o1[1] << 16); w1.y = (u32)o1[2] | ((u32)o1[3] << 16);
    w1.z = (u32)o1[4] | ((u32)o1[5] << 16); w1.w = (u32)o1[6] | ((u32)o1[7] << 16);
    w2.x = (u32)o2[0] | ((u32)o2[1] << 16); w2.y = (u32)o2[2] | ((u32)o2[3] << 16);
    w2.z = (u32)o2[4] | ((u32)o2[5] << 16); w2.w = (u32)o2[6] | ((u32)o2[7] << 16);
    *(uint4*)(dst + 8 * a) = w1;
    *(uint4*)(dst + 32 + 8 * a) = w2;
}

__global__ void qk_prep(const float* __restrict__ xq, const float* __restrict__ xk,
                        const float* __restrict__ ctab, const float* __restrict__ stab,
                        u16* __restrict__ Qn, u16* __restrict__ Kn) {
    int bid = blockIdx.x;             // 2048 = 32 bh * 64 s-tiles
    int bh = bid >> 6, stile = bid & 63;
    int b = bh >> 4, h = bh & 15;
    int t = threadIdx.x;
    int lr = t >> 2, a = t & 3;
    int s = stile * 64 + lr;
    size_t inoff = ((size_t)(b * SEQ + s)) * DIM + h * HD;
    size_t outoff = ((size_t)bh * SEQ + s) * HD;
    const float* cr = ctab + (size_t)s * 32;
    const float* sr = stab + (size_t)s * 32;
    // fold 1/sqrt(64) * log2(e) into Q so softmax is raw exp2 with NO max shift
    norm_rope_row(xq + inoff, cr, sr, 0.125f * 1.44269504f, Qn + outoff, a);
    norm_rope_row(xk + inoff, cr, sr, 1.0f, Kn + outoff, a);
}

// ---------------- v: bf16 + transpose to Vt[bh][dim][s] ----------------
__global__ void v_prep(const float* __restrict__ xv, u16* __restrict__ Vt) {
    __shared__ u16 tile[64][66];
    int bid = blockIdx.x;
    int bh = bid >> 6, stile = bid & 63;
    int b = bh >> 4, h = bh & 15;
    int t = threadIdx.x;
    int lr = t >> 2, a = t & 3;
    int s = stile * 64 + lr;
    const float* vrow = xv + ((size_t)(b * SEQ + s)) * DIM + h * HD + 16 * a;
#pragma unroll
    for (int c = 0; c < 4; ++c) {
        float4 w = *(const float4*)(vrow + 4 * c);
        tile[lr][16 * a + 4 * c + 0] = f2bf(w.x);
        tile[lr][16 * a + 4 * c + 1] = f2bf(w.y);
        tile[lr][16 * a + 4 * c + 2] = f2bf(w.z);
        tile[lr][16 * a + 4 * c + 3] = f2bf(w.w);
    }
    __syncthreads();
    int d = t >> 2;
    u32 pk[8];
#pragma unroll
    for (int i = 0; i < 8; ++i) {
        u16 lo = tile[16 * a + 2 * i][d];
        u16 hi = tile[16 * a + 2 * i + 1][d];
        pk[i] = (u32)lo | ((u32)hi << 16);
    }
    u16* dst = Vt + ((size_t)bh * HD + d) * SEQ + stile * 64 + 16 * a;
    *(uint4*)(dst) = make_uint4(pk[0], pk[1], pk[2], pk[3]);
    *(uint4*)(dst + 8) = make_uint4(pk[4], pk[5], pk[6], pk[7]);
}

// ---------------- attention: swapped 32x32x16, fixed-shift softmax, rotated K/V pipeline ----------------
// grid = 32 bh * 32 q-tiles(128 rows) = 1024 blocks; 4 waves/block, each wave 32 q-rows
// launch_bounds (256,4): unified VGPR+AGPR cap 128 — proven no-spill; tighter caps spilled
// the AGPR accumulators to scratch (r5/r6), looser (256,3) ballooned usage and lost occupancy (r8)
__global__ __launch_bounds__(256, 4) void attn_kernel(const u16* __restrict__ Qn,
                                                      const u16* __restrict__ Kn,
                                                      const u16* __restrict__ Vt,
                                                      float* __restrict__ out) {
    int phys = blockIdx.x;
    int logical = (phys & 7) * 128 + (phys >> 3);   // bijective: 1024 = 8 * 128
    int bh = logical >> 5, qt = logical & 31;
    int b = bh >> 4, h = bh & 15;
    int tid = threadIdx.x;
    int w = tid >> 6, l = tid & 63;
    int q = l & 31, hi = l >> 5;
    int qw0 = qt * 128 + w * 32;
    const u16* Qh = Qn + (size_t)bh * SEQ * HD;
    const u16* Kh = Kn + (size_t)bh * SEQ * HD;
    const u16* Vh = Vt + (size_t)bh * HD * SEQ;

    // Q B-fragments (col = q = lane&31, k-slot (hi,j) = dim kd*16 + hi*8 + j)
    const u16* qp = Qh + (size_t)(qw0 + q) * HD + hi * 8;
    bf16x8 qf0 = *(const bf16x8*)(qp);
    bf16x8 qf1 = *(const bf16x8*)(qp + 16);
    bf16x8 qf2 = *(const bf16x8*)(qp + 32);
    bf16x8 qf3 = *(const bf16x8*)(qp + 48);

    f32x16 acc0, acc1;
#pragma unroll
    for (int i = 0; i < 16; ++i) { acc0[i] = 0.f; acc1[i] = 0.f; }
    float l_ = 0.f;

    int t0 = (qw0 - (WIN - 1)) >> 5; if (t0 < 0) t0 = 0;
    int t1 = qw0 >> 5;
    int dq = qw0 + q;

    const u16* vrow0 = Vh + (size_t)(q) * SEQ;            // d = lane&31
    const u16* vrow1 = Vh + (size_t)(32 + q) * SEQ;       // d = 32 + lane&31
    const u16* krow = Kh + (size_t)q * HD + hi * 8;       // + kv0*HD per tile

    // loop-carried K/V fragments: loads for tile t+1 are issued mid-tile t into the
    // SAME registers (dead after their MFMAs) -> depth-1 pipeline at zero register cost
    bf16x8 kr[4], vr[4];
    {
        const u16* kp = krow + (size_t)(t0 << 5) * HD;
        kr[0] = *(const bf16x8*)(kp);
        kr[1] = *(const bf16x8*)(kp + 16);
        kr[2] = *(const bf16x8*)(kp + 32);
        kr[3] = *(const bf16x8*)(kp + 48);
        const u16* v0p = vrow0 + (t0 << 5) + hi * 8;
        const u16* v1p = vrow1 + (t0 << 5) + hi * 8;
        vr[0] = *(const bf16x8*)(v0p);
        vr[1] = *(const bf16x8*)(v0p + 16);
        vr[2] = *(const bf16x8*)(v1p);
        vr[3] = *(const bf16x8*)(v1p + 16);
    }

    for (int t = t0; t <= t1; ++t) {
        int kv0 = t << 5;
        bool more = t < t1;
        bool mask = (t == t0) || (t == t1);

        // --- QK^T (swapped): S^T[key][q] ---
        f32x16 st;
#pragma unroll
        for (int i = 0; i < 16; ++i) st[i] = 0.f;
        st = __builtin_amdgcn_mfma_f32_32x32x16_bf16(kr[0], qf0, st, 0, 0, 0);
        st = __builtin_amdgcn_mfma_f32_32x32x16_bf16(kr[1], qf1, st, 0, 0, 0);
        st = __builtin_amdgcn_mfma_f32_32x32x16_bf16(kr[2], qf2, st, 0, 0, 0);
        st = __builtin_amdgcn_mfma_f32_32x32x16_bf16(kr[3], qf3, st, 0, 0, 0);

        // --- prefetch next K into the now-dead kr (hides under softmax+PV) ---
        if (more) {
            const u16* kp = krow + (size_t)(kv0 + 32) * HD;
            kr[0] = *(const bf16x8*)(kp);
            kr[1] = *(const bf16x8*)(kp + 16);
            kr[2] = *(const bf16x8*)(kp + 32);
            kr[3] = *(const bf16x8*)(kp + 48);
        }

        // --- fused softmax: mask + exp2 + sum + pack (no p[16] array) ---
        // |S| <= 0.18 (l2-normed q,k) so p = exp2(S) directly, no max shift
        int base = dq - (kv0 + 4 * hi);     // diff = base - koff
        u32 wd[8];
        float l0 = 0.f, l1 = 0.f;
#pragma unroll
        for (int i = 0; i < 8; ++i) {
            int r0 = 2 * i, r1 = 2 * i + 1;
            float e0 = exp2f(st[r0]);
            float e1 = exp2f(st[r1]);
            if (mask) {
                int k0off = (r0 & 3) + 8 * (r0 >> 2);
                int k1off = (r1 & 3) + 8 * (r1 >> 2);
                e0 = ((u32)(base - k0off) < (u32)WIN) ? e0 : 0.f;
                e1 = ((u32)(base - k1off) < (u32)WIN) ? e1 : 0.f;
            }
            l0 += e0; l1 += e1;
            wd[i] = cvtpk(e0, e1);
        }
        l_ += l0 + l1;

        // --- P^T B-fragment via permlane32_swap (T12) ---
        u32x4 b1, b2;
#if __has_builtin(__builtin_amdgcn_permlane32_swap)
        u32x2 sA = __builtin_amdgcn_permlane32_swap(wd[0], wd[2], false, false);
        u32x2 sB = __builtin_amdgcn_permlane32_swap(wd[1], wd[3], false, false);
        u32x2 sC = __builtin_amdgcn_permlane32_swap(wd[4], wd[6], false, false);
        u32x2 sD = __builtin_amdgcn_permlane32_swap(wd[5], wd[7], false, false);
        b1 = (u32x4){ sA[0], sB[0], sA[1], sB[1] };
        b2 = (u32x4){ sC[0], sD[0], sC[1], sD[1] };
#else
        u32 e0 = __shfl_xor(hi ? wd[0] : wd[2], 32);
        u32 e1 = __shfl_xor(hi ? wd[1] : wd[3], 32);
        u32 e2 = __shfl_xor(hi ? wd[4] : wd[6], 32);
        u32 e3 = __shfl_xor(hi ? wd[5] : wd[7], 32);
        b1 = (u32x4){ hi ? e0 : wd[0], hi ? e1 : wd[1], hi ? wd[2] : e0, hi ? wd[3] : e1 };
        b2 = (u32x4){ hi ? e2 : wd[4], hi ? e3 : wd[5], hi ? wd[6] : e2, hi ? wd[7] : e3 };
#endif
        bf16x8 pb1 = __builtin_bit_cast(bf16x8, b1);
        bf16x8 pb2 = __builtin_bit_cast(bf16x8, b2);

        // --- PV (swapped): O^T[d][q] += V^T P^T ---
        acc0 = __builtin_amdgcn_mfma_f32_32x32x16_bf16(vr[0], pb1, acc0, 0, 0, 0);
        acc0 = __builtin_amdgcn_mfma_f32_32x32x16_bf16(vr[1], pb2, acc0, 0, 0, 0);
        acc1 = __builtin_amdgcn_mfma_f32_32x32x16_bf16(vr[2], pb1, acc1, 0, 0, 0);
        acc1 = __builtin_amdgcn_mfma_f32_32x32x16_bf16(vr[3], pb2, acc1, 0, 0, 0);

        // --- prefetch next V into the now-dead vr (hides until next tile's PV) ---
        if (more) {
            const u16* v0p = vrow0 + kv0 + 32 + hi * 8;
            const u16* v1p = vrow1 + kv0 + 32 + hi * 8;
            vr[0] = *(const bf16x8*)(v0p);
            vr[1] = *(const bf16x8*)(v0p + 16);
            vr[2] = *(const bf16x8*)(v1p);
            vr[3] = *(const bf16x8*)(v1p + 16);
        }
    }

    l_ += __shfl_xor(l_, 32);
    float inv = 1.0f / l_;
    float* orow = out + ((size_t)(b * SEQ + dq)) * DIM + h * HD;
#pragma unroll
    for (int g = 0; g < 4; ++g) {
        float4 v0 = { acc0[4 * g + 0] * inv, acc0[4 * g + 1] * inv,
                      acc0[4 * g + 2] * inv, acc0[4 * g + 3] * inv };
        float4 v1 = { acc1[4 * g + 0] * inv, acc1[4 * g + 1] * inv,
                      acc1[4 * g + 2] * inv, acc1[4 * g + 3] * inv };
        *(float4*)(orow + 8 * g + 4 * hi) = v0;          // d = 8g + 4hi + 0..3
        *(float4*)(orow + 32 + 8 * g + 4 * hi) = v1;     // d = 32 + 8g + 4hi + 0..3
    }
}

extern "C" void kernel_launch(void* const* d_in, const int* in_sizes, int n_in,
                              void* d_out, int out_size, void* d_ws, size_t ws_size,
                              hipStream_t stream) {
    (void)in_sizes; (void)n_in; (void)out_size; (void)ws_size;
    const float* xq = (const float*)d_in[0];
    const float* xk = (const float*)d_in[1];
    const float* xv = (const float*)d_in[2];
    float* out = (float*)d_out;

    const size_t HEADS_ELEMS = (size_t)NB * NH * SEQ * HD;   // 8,388,608
    u16* Qn = (u16*)d_ws;
    u16* Kn = Qn + HEADS_ELEMS;
    u16* Vt = Kn + HEADS_ELEMS;
    float* ctab = (float*)(Vt + HEADS_ELEMS);
    float* stab = ctab + (size_t)SEQ * 32;

    trig_kernel<<<dim3(512), dim3(256), 0, stream>>>(ctab, stab);
    qk_prep<<<dim3(2048), dim3(256), 0, stream>>>(xq, xk, ctab, stab, Qn, Kn);
    v_prep<<<dim3(2048), dim3(256), 0, stream>>>(xv, Vt);
    attn_kernel<<<dim3(1024), dim3(256), 0, stream>>>(Qn, Kn, Vt, out);
}

// Round 10
// 79.936 us; speedup vs baseline: 1.5383x; 1.3141x over previous
//
#include <hip/hip_runtime.h>

#define NB 2
#define NH 16
#define SEQ 4096
#define HD 64
#define DIM 1024
#define WIN 512

typedef float f32x16 __attribute__((ext_vector_type(16)));
typedef short bf16x8 __attribute__((ext_vector_type(8)));
typedef unsigned int u32x4 __attribute__((ext_vector_type(4)));
typedef unsigned int u32x2 __attribute__((ext_vector_type(2)));
typedef unsigned short u16;
typedef unsigned int u32;

__device__ __forceinline__ u16 f2bf(float x) {
    u32 u = __float_as_uint(x);
    u += 0x7FFFu + ((u >> 16) & 1u);
    return (u16)(u >> 16);
}

// pack 2 f32 -> 1 u32 of 2 bf16 (RNE) in one VALU op
__device__ __forceinline__ u32 cvtpk(float lo, float hi) {
    u32 r;
    asm("v_cvt_pk_bf16_f32 %0, %1, %2" : "=v"(r) : "v"(lo), "v"(hi));
    return r;
}

// ---------------- trig table ----------------
__global__ void trig_kernel(float* __restrict__ ct, float* __restrict__ st) {
    int idx = blockIdx.x * 256 + threadIdx.x;   // 4096*32
    int s = idx >> 5, j = idx & 31;
    float inv = powf(1.0f / 10000.0f, (float)j * (1.0f / 32.0f));
    float ang = (float)s * inv;
    ct[idx] = cosf(ang);
    st[idx] = sinf(ang);
}

// ---------------- q/k: l2-normalize + rope + scale -> bf16, head-major ----------------
__device__ __forceinline__ void norm_rope_row(const float* __restrict__ row,
                                              const float* __restrict__ cr,
                                              const float* __restrict__ sr,
                                              float scale, u16* __restrict__ dst, int a) {
    float4 u0 = *(const float4*)(row + 8 * a);
    float4 u1 = *(const float4*)(row + 8 * a + 4);
    float4 v0 = *(const float4*)(row + 32 + 8 * a);
    float4 v1 = *(const float4*)(row + 32 + 8 * a + 4);
    float x1[8] = {u0.x, u0.y, u0.z, u0.w, u1.x, u1.y, u1.z, u1.w};
    float x2[8] = {v0.x, v0.y, v0.z, v0.w, v1.x, v1.y, v1.z, v1.w};
    float ss = 0.f;
#pragma unroll
    for (int i = 0; i < 8; ++i) ss += x1[i] * x1[i] + x2[i] * x2[i];
    ss += __shfl_xor(ss, 1);
    ss += __shfl_xor(ss, 2);
    float rn = scale / fmaxf(sqrtf(ss), 1e-6f);
    u16 o1[8], o2[8];
#pragma unroll
    for (int i = 0; i < 8; ++i) {
        float c = cr[8 * a + i], sn = sr[8 * a + i];
        o1[i] = f2bf((x1[i] * c + x2[i] * sn) * rn);
        o2[i] = f2bf((x2[i] * c - x1[i] * sn) * rn);
    }
    uint4 w1, w2;
    w1.x = (u32)o1[0] | ((u32)o1[1] << 16); w1.y = (u32)o1[2] | ((u32)o1[3] << 16);
    w1.z = (u32)o1[4] | ((u32)o1[5] << 16); w1.w = (u32)o1[6] | ((u32)o1[7] << 16);
    w2.x = (u32)o2[0] | ((u32)o2[1] << 16); w2.y = (u32)o2[2] | ((u32)o2[3] << 16);
    w2.z = (u32)o2[4] | ((u32)o2[5] << 16); w2.w = (u32)o2[6] | ((u32)o2[7] << 16);
    *(uint4*)(dst + 8 * a) = w1;
    *(uint4*)(dst + 32 + 8 * a) = w2;
}

__global__ void qk_prep(const float* __restrict__ xq, const float* __restrict__ xk,
                        const float* __restrict__ ctab, const float* __restrict__ stab,
                        u16* __restrict__ Qn, u16* __restrict__ Kn) {
    int bid = blockIdx.x;             // 2048 = 32 bh * 64 s-tiles
    int bh = bid >> 6, stile = bid & 63;
    int b = bh >> 4, h = bh & 15;
    int t = threadIdx.x;
    int lr = t >> 2, a = t & 3;
    int s = stile * 64 + lr;
    size_t inoff = ((size_t)(b * SEQ + s)) * DIM + h * HD;
    size_t outoff = ((size_t)bh * SEQ + s) * HD;
    const float* cr = ctab + (size_t)s * 32;
    const float* sr = stab + (size_t)s * 32;
    // fold 1/sqrt(64) * log2(e) into Q so softmax is raw exp2 with NO max shift
    norm_rope_row(xq + inoff, cr, sr, 0.125f * 1.44269504f, Qn + outoff, a);
    norm_rope_row(xk + inoff, cr, sr, 1.0f, Kn + outoff, a);
}

// ---------------- v: bf16 + transpose to Vt[bh][dim][s] ----------------
__global__ void v_prep(const float* __restrict__ xv, u16* __restrict__ Vt) {
    __shared__ u16 tile[64][66];
    int bid = blockIdx.x;
    int bh = bid >> 6, stile = bid & 63;
    int b = bh >> 4, h = bh & 15;
    int t = threadIdx.x;
    int lr = t >> 2, a = t & 3;
    int s = stile * 64 + lr;
    const float* vrow = xv + ((size_t)(b * SEQ + s)) * DIM + h * HD + 16 * a;
#pragma unroll
    for (int c = 0; c < 4; ++c) {
        float4 w = *(const float4*)(vrow + 4 * c);
        tile[lr][16 * a + 4 * c + 0] = f2bf(w.x);
        tile[lr][16 * a + 4 * c + 1] = f2bf(w.y);
        tile[lr][16 * a + 4 * c + 2] = f2bf(w.z);
        tile[lr][16 * a + 4 * c + 3] = f2bf(w.w);
    }
    __syncthreads();
    int d = t >> 2;
    u32 pk[8];
#pragma unroll
    for (int i = 0; i < 8; ++i) {
        u16 lo = tile[16 * a + 2 * i][d];
        u16 hi = tile[16 * a + 2 * i + 1][d];
        pk[i] = (u32)lo | ((u32)hi << 16);
    }
    u16* dst = Vt + ((size_t)bh * HD + d) * SEQ + stile * 64 + 16 * a;
    *(uint4*)(dst) = make_uint4(pk[0], pk[1], pk[2], pk[3]);
    *(uint4*)(dst + 8) = make_uint4(pk[4], pk[5], pk[6], pk[7]);
}

// ---------------- attention: swapped 32x32x16, fixed-shift softmax, LDS-staged KV ----------------
// grid = 32 bh * 32 q-tiles(128 rows) = 1024 blocks; 4 waves/block, each wave 32 q-rows.
// Block cooperatively stages each 32-key K/V tile into LDS once (shared by ~4 waves),
// double-buffered: loads for t+1 issue BEFORE tile t's compute, ds_writes after (T14).
// K rows padded to 144B, V rows to 80B -> 8-phase bank patterns (conflict floor).
#define KROW 72   // u16 stride per K row (144B)
#define VROW 40   // u16 stride per V row (80B)
__global__ __launch_bounds__(256, 4) void attn_kernel(const u16* __restrict__ Qn,
                                                      const u16* __restrict__ Kn,
                                                      const u16* __restrict__ Vt,
                                                      float* __restrict__ out) {
    __shared__ __align__(16) u16 Kl[2][32 * KROW];   //  9216 B
    __shared__ __align__(16) u16 Vl[2][64 * VROW];   // 10240 B
    int phys = blockIdx.x;
    int logical = (phys & 7) * 128 + (phys >> 3);   // bijective: 1024 = 8 * 128
    int bh = logical >> 5, qt = logical & 31;
    int b = bh >> 4, h = bh & 15;
    int tid = threadIdx.x;
    int w = tid >> 6, l = tid & 63;
    int q = l & 31, hi = l >> 5;
    int qblk = qt * 128;
    int qw0 = qblk + w * 32;
    const u16* Qh = Qn + (size_t)bh * SEQ * HD;
    const u16* Kh = Kn + (size_t)bh * SEQ * HD;
    const u16* Vh = Vt + (size_t)bh * HD * SEQ;

    // Q B-fragments (col = q = lane&31, k-slot (hi,j) = dim kd*16 + hi*8 + j)
    const u16* qp = Qh + (size_t)(qw0 + q) * HD + hi * 8;
    bf16x8 qf0 = *(const bf16x8*)(qp);
    bf16x8 qf1 = *(const bf16x8*)(qp + 16);
    bf16x8 qf2 = *(const bf16x8*)(qp + 32);
    bf16x8 qf3 = *(const bf16x8*)(qp + 48);

    f32x16 acc0, acc1;
#pragma unroll
    for (int i = 0; i < 16; ++i) { acc0[i] = 0.f; acc1[i] = 0.f; }
    float l_ = 0.f;

    // wave's own tile window
    int tw0 = (qw0 - (WIN - 1)) >> 5; if (tw0 < 0) tw0 = 0;
    int tw1 = qw0 >> 5;
    // block's union window
    int bt0 = (qblk - (WIN - 1)) >> 5; if (bt0 < 0) bt0 = 0;
    int bt1 = (qblk + 96) >> 5;
    int dq = qw0 + q;

    // staging assignments (per thread, constant across tiles)
    int krow = tid >> 3, kc = (tid & 7) * 8;        // K: 32 rows x 8 chunks of 8 u16
    int vrw  = tid >> 2, vc = (tid & 3) * 8;        // V: 64 rows x 4 chunks of 8 u16
    const u16* kgl = Kh + (size_t)krow * HD + kc;   // + kv0*HD per tile
    const u16* vgl = Vh + (size_t)vrw * SEQ + vc;   // + kv0 per tile
    u16* kls0 = &Kl[0][krow * KROW + kc];
    u16* kls1 = &Kl[1][krow * KROW + kc];
    u16* vls0 = &Vl[0][vrw * VROW + vc];
    u16* vls1 = &Vl[1][vrw * VROW + vc];

    // compute-phase LDS read bases
    const u16* krd0 = &Kl[0][q * KROW + hi * 8];
    const u16* krd1 = &Kl[1][q * KROW + hi * 8];
    const u16* vrd0a = &Vl[0][q * VROW + hi * 8];
    const u16* vrd0b = &Vl[0][(32 + q) * VROW + hi * 8];
    const u16* vrd1a = &Vl[1][q * VROW + hi * 8];
    const u16* vrd1b = &Vl[1][(32 + q) * VROW + hi * 8];

    // prologue: stage tile bt0 into buffer 0
    {
        uint4 gk = *(const uint4*)(kgl + ((size_t)bt0 << 5) * HD);
        uint4 gv = *(const uint4*)(vgl + (bt0 << 5));
        *(uint4*)kls0 = gk;
        *(uint4*)vls0 = gv;
    }
    __syncthreads();

    int c = 0;
    for (int t = bt0; t <= bt1; ++t) {
        int kv0 = t << 5;
        bool more = t < bt1;
        uint4 gk, gv;
        if (more) {   // issue next-tile global loads BEFORE compute (latency hides under it)
            gk = *(const uint4*)(kgl + ((size_t)(kv0 + 32)) * HD);
            gv = *(const uint4*)(vgl + (kv0 + 32));
        }

        if (t >= tw0 && t <= tw1) {
            bool mask = (t == tw0) || (t == tw1);
            const u16* kr = c ? krd1 : krd0;
            const u16* va = c ? vrd1a : vrd0a;
            const u16* vb = c ? vrd1b : vrd0b;

            bf16x8 k0 = *(const bf16x8*)(kr);
            bf16x8 k1 = *(const bf16x8*)(kr + 16);
            bf16x8 k2 = *(const bf16x8*)(kr + 32);
            bf16x8 k3 = *(const bf16x8*)(kr + 48);

            f32x16 st;
#pragma unroll
            for (int i = 0; i < 16; ++i) st[i] = 0.f;
            st = __builtin_amdgcn_mfma_f32_32x32x16_bf16(k0, qf0, st, 0, 0, 0);
            st = __builtin_amdgcn_mfma_f32_32x32x16_bf16(k1, qf1, st, 0, 0, 0);
            st = __builtin_amdgcn_mfma_f32_32x32x16_bf16(k2, qf2, st, 0, 0, 0);
            st = __builtin_amdgcn_mfma_f32_32x32x16_bf16(k3, qf3, st, 0, 0, 0);

            // V fragments from LDS (cheap, issued during softmax window)
            bf16x8 va0 = *(const bf16x8*)(va);
            bf16x8 va1 = *(const bf16x8*)(va + 16);
            bf16x8 vb0 = *(const bf16x8*)(vb);
            bf16x8 vb1 = *(const bf16x8*)(vb + 16);

            // fused softmax: |S| <= 0.18 (l2-normed q,k) -> p = exp2(S), no max shift
            int base = dq - (kv0 + 4 * hi);
            u32 wd[8];
            float l0 = 0.f, l1 = 0.f;
#pragma unroll
            for (int i = 0; i < 8; ++i) {
                int r0 = 2 * i, r1 = 2 * i + 1;
                float e0 = exp2f(st[r0]);
                float e1 = exp2f(st[r1]);
                if (mask) {
                    int k0off = (r0 & 3) + 8 * (r0 >> 2);
                    int k1off = (r1 & 3) + 8 * (r1 >> 2);
                    e0 = ((u32)(base - k0off) < (u32)WIN) ? e0 : 0.f;
                    e1 = ((u32)(base - k1off) < (u32)WIN) ? e1 : 0.f;
                }
                l0 += e0; l1 += e1;
                wd[i] = cvtpk(e0, e1);
            }
            l_ += l0 + l1;

            // P^T B-fragment via permlane32_swap (T12)
            u32x4 b1, b2;
#if __has_builtin(__builtin_amdgcn_permlane32_swap)
            u32x2 sA = __builtin_amdgcn_permlane32_swap(wd[0], wd[2], false, false);
            u32x2 sB = __builtin_amdgcn_permlane32_swap(wd[1], wd[3], false, false);
            u32x2 sC = __builtin_amdgcn_permlane32_swap(wd[4], wd[6], false, false);
            u32x2 sD = __builtin_amdgcn_permlane32_swap(wd[5], wd[7], false, false);
            b1 = (u32x4){ sA[0], sB[0], sA[1], sB[1] };
            b2 = (u32x4){ sC[0], sD[0], sC[1], sD[1] };
#else
            u32 e0 = __shfl_xor(hi ? wd[0] : wd[2], 32);
            u32 e1 = __shfl_xor(hi ? wd[1] : wd[3], 32);
            u32 e2 = __shfl_xor(hi ? wd[4] : wd[6], 32);
            u32 e3 = __shfl_xor(hi ? wd[5] : wd[7], 32);
            b1 = (u32x4){ hi ? e0 : wd[0], hi ? e1 : wd[1], hi ? wd[2] : e0, hi ? wd[3] : e1 };
            b2 = (u32x4){ hi ? e2 : wd[4], hi ? e3 : wd[5], hi ? wd[6] : e2, hi ? wd[7] : e3 };
#endif
            bf16x8 pb1 = __builtin_bit_cast(bf16x8, b1);
            bf16x8 pb2 = __builtin_bit_cast(bf16x8, b2);

            acc0 = __builtin_amdgcn_mfma_f32_32x32x16_bf16(va0, pb1, acc0, 0, 0, 0);
            acc0 = __builtin_amdgcn_mfma_f32_32x32x16_bf16(va1, pb2, acc0, 0, 0, 0);
            acc1 = __builtin_amdgcn_mfma_f32_32x32x16_bf16(vb0, pb1, acc1, 0, 0, 0);
            acc1 = __builtin_amdgcn_mfma_f32_32x32x16_bf16(vb1, pb2, acc1, 0, 0, 0);
        }

        if (more) {   // write staged tile to the other buffer (T14: waitcnt lands here)
            *(uint4*)(c ? kls0 : kls1) = gk;
            *(uint4*)(c ? vls0 : vls1) = gv;
        }
        __syncthreads();
        c ^= 1;
    }

    l_ += __shfl_xor(l_, 32);
    float inv = 1.0f / l_;
    float* orow = out + ((size_t)(b * SEQ + dq)) * DIM + h * HD;
#pragma unroll
    for (int g = 0; g < 4; ++g) {
        float4 v0 = { acc0[4 * g + 0] * inv, acc0[4 * g + 1] * inv,
                      acc0[4 * g + 2] * inv, acc0[4 * g + 3] * inv };
        float4 v1 = { acc1[4 * g + 0] * inv, acc1[4 * g + 1] * inv,
                      acc1[4 * g + 2] * inv, acc1[4 * g + 3] * inv };
        *(float4*)(orow + 8 * g + 4 * hi) = v0;          // d = 8g + 4hi + 0..3
        *(float4*)(orow + 32 + 8 * g + 4 * hi) = v1;     // d = 32 + 8g + 4hi + 0..3
    }
}

extern "C" void kernel_launch(void* const* d_in, const int* in_sizes, int n_in,
                              void* d_out, int out_size, void* d_ws, size_t ws_size,
                              hipStream_t stream) {
    (void)in_sizes; (void)n_in; (void)out_size; (void)ws_size;
    const float* xq = (const float*)d_in[0];
    const float* xk = (const float*)d_in[1];
    const float* xv = (const float*)d_in[2];
    float* out = (float*)d_out;

    const size_t HEADS_ELEMS = (size_t)NB * NH * SEQ * HD;   // 8,388,608
    u16* Qn = (u16*)d_ws;
    u16* Kn = Qn + HEADS_ELEMS;
    u16* Vt = Kn + HEADS_ELEMS;
    float* ctab = (float*)(Vt + HEADS_ELEMS);
    float* stab = ctab + (size_t)SEQ * 32;

    trig_kernel<<<dim3(512), dim3(256), 0, stream>>>(ctab, stab);
    qk_prep<<<dim3(2048), dim3(256), 0, stream>>>(xq, xk, ctab, stab, Qn, Kn);
    v_prep<<<dim3(2048), dim3(256), 0, stream>>>(xv, Vt);
    attn_kernel<<<dim3(1024), dim3(256), 0, stream>>>(Qn, Kn, Vt, out);
}